// Round 1
// baseline (1232.094 us; speedup 1.0000x reference)
//
#include <hip/hip_runtime.h>

// bf16 storage type = ushort (raw bits); avoids hip_bf16.h dependency.
typedef __bf16 bf16x8 __attribute__((ext_vector_type(8)));
typedef float f32x4 __attribute__((ext_vector_type(4)));

#define MFMA16(a, b, c) __builtin_amdgcn_mfma_f32_16x16x32_bf16((a), (b), (c), 0, 0, 0)

__device__ __forceinline__ unsigned short f2bf(float f) {
    // round-to-nearest-even bf16 (finite inputs)
    unsigned int u = __float_as_uint(f);
    u += 0x7fffu + ((u >> 16) & 1u);
    return (unsigned short)(u >> 16);
}

__device__ __forceinline__ void gload16(const unsigned short* g, unsigned short* l) {
    // async global->LDS, 16B per lane; LDS dest = wave-uniform base + lane*16
    __builtin_amdgcn_global_load_lds(
        (__attribute__((address_space(1))) void*)(void*)g,
        (__attribute__((address_space(3))) void*)(void*)l,
        16, 0, 0);
}

// ---------------- prep: x fp32 -> bf16 ----------------
__global__ void cast_x_kernel(const float4* __restrict__ x, ushort4* __restrict__ xb) {
    const size_t i = (size_t)blockIdx.x * 256 + threadIdx.x;
    const float4 v = x[i];
    ushort4 o;
    o.x = f2bf(v.x); o.y = f2bf(v.y); o.z = f2bf(v.z); o.w = f2bf(v.w);
    xb[i] = o;
}

// ---------------- prep: WT[n,k] = W[k,n] + sum_r A[k,r]*B2[r,n], bf16 out ----
// W: [K,N] fp32, A: [K,16] fp32, B2: [16,N] fp32, WT: [N,K] bf16
__global__ void prep_wT(const float* __restrict__ W, const float* __restrict__ A,
                        const float* __restrict__ B2, unsigned short* __restrict__ WT,
                        const int K, const int N) {
    __shared__ float tile[64][65];
    __shared__ float As[64][16];
    __shared__ float Bs[16][64];
    const int t = threadIdx.x;         // 256 threads
    const int k0 = blockIdx.x * 64;
    const int n0 = blockIdx.y * 64;

    for (int i = t; i < 64 * 16; i += 256)
        As[i >> 4][i & 15] = A[(size_t)(k0 + (i >> 4)) * 16 + (i & 15)];
    for (int i = t; i < 16 * 64; i += 256)
        Bs[i >> 6][i & 63] = B2[(size_t)(i >> 6) * N + n0 + (i & 63)];
    __syncthreads();

    const int c = t & 63;
    const int r0 = t >> 6;
    for (int rr = 0; rr < 64; rr += 4) {
        const int r = rr + r0;
        float v = W[(size_t)(k0 + r) * N + n0 + c];
#pragma unroll
        for (int q = 0; q < 16; ++q) v += As[r][q] * Bs[q][c];
        tile[r][c] = v;
    }
    __syncthreads();
    for (int rr = 0; rr < 64; rr += 4) {
        const int r = rr + r0;
        WT[(size_t)(n0 + r) * K + k0 + c] = f2bf(tile[c][r]);
    }
}

// ---------------- fused gate+up GEMM + relu-gate epilogue ----------------
// Xb: [M,2048] bf16, WgT/WuT: [8192,2048] bf16 (row n, contiguous k)
// X3[m,f] = relu(Xb@WgT^T + bg) * (Xb@WuT^T + bu), bf16
__global__ __launch_bounds__(256, 2)
void gemm_gateup(const unsigned short* __restrict__ Xb,
                 const unsigned short* __restrict__ WgT,
                 const unsigned short* __restrict__ WuT,
                 const float* __restrict__ bg, const float* __restrict__ bu,
                 unsigned short* __restrict__ X3) {
    constexpr int K = 2048, F = 8192;
    __shared__ __align__(16) unsigned short As[128 * 32];
    __shared__ __align__(16) unsigned short Bg[128 * 32];
    __shared__ __align__(16) unsigned short Bu[128 * 32];

    const int tid = threadIdx.x;
    const int lane = tid & 63;
    const int wave = tid >> 6;
    const int wm = (wave >> 1) * 64;
    const int wn = (wave & 1) * 64;
    const int l16 = lane & 15;
    const int quad = lane >> 4;
    const int q8 = quad * 8;

    const int m0 = blockIdx.x * 128;
    const int n0 = blockIdx.y * 128;

    const unsigned short* Ag = Xb + (size_t)m0 * K;
    const unsigned short* Gg = WgT + (size_t)n0 * K;
    const unsigned short* Ug = WuT + (size_t)n0 * K;

    // staging: 512 chunks of 16B per tile; thread stages chunks tid and tid+256
    const int c1 = tid, c2 = tid + 256;
    const int r1 = c1 >> 2, o1 = (c1 & 3) * 8;
    const int r2 = c2 >> 2, o2 = (c2 & 3) * 8;

    f32x4 accg[4][4] = {};
    f32x4 accu[4][4] = {};

    for (int k0 = 0; k0 < K; k0 += 32) {
        gload16(Ag + (size_t)r1 * K + k0 + o1, As + c1 * 8);
        gload16(Ag + (size_t)r2 * K + k0 + o2, As + c2 * 8);
        gload16(Gg + (size_t)r1 * K + k0 + o1, Bg + c1 * 8);
        gload16(Gg + (size_t)r2 * K + k0 + o2, Bg + c2 * 8);
        gload16(Ug + (size_t)r1 * K + k0 + o1, Bu + c1 * 8);
        gload16(Ug + (size_t)r2 * K + k0 + o2, Bu + c2 * 8);
        __syncthreads();  // drains vmcnt(0): LDS tiles ready
        bf16x8 af[4], gf[4], uf[4];
#pragma unroll
        for (int i = 0; i < 4; ++i) {
            af[i] = *(const bf16x8*)(As + (wm + i * 16 + l16) * 32 + q8);
            gf[i] = *(const bf16x8*)(Bg + (wn + i * 16 + l16) * 32 + q8);
            uf[i] = *(const bf16x8*)(Bu + (wn + i * 16 + l16) * 32 + q8);
        }
#pragma unroll
        for (int i = 0; i < 4; ++i)
#pragma unroll
            for (int j = 0; j < 4; ++j) {
                accg[i][j] = MFMA16(af[i], gf[j], accg[i][j]);
                accu[i][j] = MFMA16(af[i], uf[j], accu[i][j]);
            }
        __syncthreads();  // all reads done before next stage overwrites
    }

    // epilogue: C/D layout col = lane&15, row = quad*4 + reg  [m89/m91-verified]
#pragma unroll
    for (int j = 0; j < 4; ++j) {
        const int col = n0 + wn + j * 16 + l16;
        const float bgv = bg[col];
        const float buv = bu[col];
#pragma unroll
        for (int i = 0; i < 4; ++i) {
            const int rowb = m0 + wm + i * 16 + quad * 4;
#pragma unroll
            for (int r = 0; r < 4; ++r) {
                float g = accg[i][j][r] + bgv;
                float u = accu[i][j][r] + buv;
                g = g > 0.f ? g : 0.f;
                X3[(size_t)(rowb + r) * F + col] = f2bf(g * u);
            }
        }
    }
}

// ---------------- down GEMM: out = X3@WdT^T + bd, fp32 out ----------------
// X3: [M,8192] bf16, WdT: [2048,8192] bf16
__global__ __launch_bounds__(256, 2)
void gemm_down(const unsigned short* __restrict__ X3,
               const unsigned short* __restrict__ WdT,
               const float* __restrict__ bd, float* __restrict__ out) {
    constexpr int K = 8192, N = 2048;
    __shared__ __align__(16) unsigned short As[128 * 32];
    __shared__ __align__(16) unsigned short Bs[128 * 32];

    const int tid = threadIdx.x;
    const int lane = tid & 63;
    const int wave = tid >> 6;
    const int wm = (wave >> 1) * 64;
    const int wn = (wave & 1) * 64;
    const int l16 = lane & 15;
    const int quad = lane >> 4;
    const int q8 = quad * 8;

    const int m0 = blockIdx.x * 128;
    const int n0 = blockIdx.y * 128;

    const unsigned short* Ag = X3 + (size_t)m0 * K;
    const unsigned short* Bgp = WdT + (size_t)n0 * K;

    const int c1 = tid, c2 = tid + 256;
    const int r1 = c1 >> 2, o1 = (c1 & 3) * 8;
    const int r2 = c2 >> 2, o2 = (c2 & 3) * 8;

    f32x4 acc[4][4] = {};

    for (int k0 = 0; k0 < K; k0 += 32) {
        gload16(Ag + (size_t)r1 * K + k0 + o1, As + c1 * 8);
        gload16(Ag + (size_t)r2 * K + k0 + o2, As + c2 * 8);
        gload16(Bgp + (size_t)r1 * K + k0 + o1, Bs + c1 * 8);
        gload16(Bgp + (size_t)r2 * K + k0 + o2, Bs + c2 * 8);
        __syncthreads();
        bf16x8 af[4], bf[4];
#pragma unroll
        for (int i = 0; i < 4; ++i) {
            af[i] = *(const bf16x8*)(As + (wm + i * 16 + l16) * 32 + q8);
            bf[i] = *(const bf16x8*)(Bs + (wn + i * 16 + l16) * 32 + q8);
        }
#pragma unroll
        for (int i = 0; i < 4; ++i)
#pragma unroll
            for (int j = 0; j < 4; ++j)
                acc[i][j] = MFMA16(af[i], bf[j], acc[i][j]);
        __syncthreads();
    }

#pragma unroll
    for (int j = 0; j < 4; ++j) {
        const int col = n0 + wn + j * 16 + l16;
        const float bdv = bd[col];
#pragma unroll
        for (int i = 0; i < 4; ++i) {
            const int rowb = m0 + wm + i * 16 + quad * 4;
#pragma unroll
            for (int r = 0; r < 4; ++r)
                out[(size_t)(rowb + r) * N + col] = acc[i][j][r] + bdv;
        }
    }
}

extern "C" void kernel_launch(void* const* d_in, const int* in_sizes, int n_in,
                              void* d_out, int out_size, void* d_ws, size_t ws_size,
                              hipStream_t stream) {
    const float* x1      = (const float*)d_in[0];
    const float* w_gate  = (const float*)d_in[1];
    const float* b_gate  = (const float*)d_in[2];
    const float* a_gate  = (const float*)d_in[3];
    const float* lb_gate = (const float*)d_in[4];
    const float* w_up    = (const float*)d_in[5];
    const float* b_up    = (const float*)d_in[6];
    const float* a_up    = (const float*)d_in[7];
    const float* lb_up   = (const float*)d_in[8];
    const float* w_down  = (const float*)d_in[9];
    const float* b_down  = (const float*)d_in[10];
    const float* a_down  = (const float*)d_in[11];
    const float* lb_down = (const float*)d_in[12];

    constexpr int M = 8192, D = 2048, F = 8192;

    // workspace layout (256 MiB total)
    char* ws = (char*)d_ws;
    unsigned short* Xb  = (unsigned short*)ws;                     // [M,D]  bf16  32 MiB
    unsigned short* WgT = (unsigned short*)(ws + 33554432ULL);     // [F,D]  bf16  32 MiB
    unsigned short* WuT = (unsigned short*)(ws + 67108864ULL);     // [F,D]  bf16  32 MiB
    unsigned short* WdT = (unsigned short*)(ws + 100663296ULL);    // [D,F]  bf16  32 MiB
    unsigned short* X3  = (unsigned short*)(ws + 134217728ULL);    // [M,F]  bf16 128 MiB

    cast_x_kernel<<<dim3((M * D) / 4 / 256), dim3(256), 0, stream>>>(
        (const float4*)x1, (ushort4*)Xb);
    prep_wT<<<dim3(D / 64, F / 64), dim3(256), 0, stream>>>(w_gate, a_gate, lb_gate, WgT, D, F);
    prep_wT<<<dim3(D / 64, F / 64), dim3(256), 0, stream>>>(w_up, a_up, lb_up, WuT, D, F);
    prep_wT<<<dim3(F / 64, D / 64), dim3(256), 0, stream>>>(w_down, a_down, lb_down, WdT, F, D);

    gemm_gateup<<<dim3(M / 128, F / 128), dim3(256), 0, stream>>>(
        Xb, WgT, WuT, b_gate, b_up, X3);
    gemm_down<<<dim3(M / 128, D / 128), dim3(256), 0, stream>>>(
        X3, WdT, b_down, (float*)d_out);
}

// Round 2
// 1206.854 us; speedup vs baseline: 1.0209x; 1.0209x over previous
//
#include <hip/hip_runtime.h>

// bf16 storage type = ushort (raw bits); avoids hip_bf16.h dependency.
typedef __bf16 bf16x8 __attribute__((ext_vector_type(8)));
typedef float f32x4 __attribute__((ext_vector_type(4)));

#define MFMA16(a, b, c) __builtin_amdgcn_mfma_f32_16x16x32_bf16((a), (b), (c), 0, 0, 0)

__device__ __forceinline__ unsigned short f2bf(float f) {
    // round-to-nearest-even bf16 (finite inputs)
    unsigned int u = __float_as_uint(f);
    u += 0x7fffu + ((u >> 16) & 1u);
    return (unsigned short)(u >> 16);
}

__device__ __forceinline__ void gload16(const unsigned short* g, unsigned short* l) {
    // async global->LDS, 16B per lane; LDS dest = wave-uniform base + lane*16
    __builtin_amdgcn_global_load_lds(
        (__attribute__((address_space(1))) void*)(void*)g,
        (__attribute__((address_space(3))) void*)(void*)l,
        16, 0, 0);
}

// LDS bank-conflict swizzle: each 128x32-elem bf16 tile is rows of 64 B = 4
// chunks of 16 B. Global chunk (r,c) is stored at LDS position (r, c ^ sw(r)).
// sw(r) = (r>>1)&3 spreads the reader's fixed-quad column across all 8
// bank-quads over 16 consecutive rows -> 2-way aliasing only (free, m136).
__device__ __forceinline__ int sw_row(int r) { return (r >> 1) & 3; }

// ---------------- prep: x fp32 -> bf16 ----------------
__global__ void cast_x_kernel(const float4* __restrict__ x, ushort4* __restrict__ xb) {
    const size_t i = (size_t)blockIdx.x * 256 + threadIdx.x;
    const float4 v = x[i];
    ushort4 o;
    o.x = f2bf(v.x); o.y = f2bf(v.y); o.z = f2bf(v.z); o.w = f2bf(v.w);
    xb[i] = o;
}

// ---------------- prep: WT[n,k] = W[k,n] + sum_r A[k,r]*B2[r,n], bf16 out ----
// W: [K,N] fp32, A: [K,16] fp32, B2: [16,N] fp32, WT: [N,K] bf16
__global__ void prep_wT(const float* __restrict__ W, const float* __restrict__ A,
                        const float* __restrict__ B2, unsigned short* __restrict__ WT,
                        const int K, const int N) {
    __shared__ float tile[64][65];
    __shared__ float As[64][16];
    __shared__ float Bs[16][64];
    const int t = threadIdx.x;         // 256 threads
    const int k0 = blockIdx.x * 64;
    const int n0 = blockIdx.y * 64;

    for (int i = t; i < 64 * 16; i += 256)
        As[i >> 4][i & 15] = A[(size_t)(k0 + (i >> 4)) * 16 + (i & 15)];
    for (int i = t; i < 16 * 64; i += 256)
        Bs[i >> 6][i & 63] = B2[(size_t)(i >> 6) * N + n0 + (i & 63)];
    __syncthreads();

    const int c = t & 63;
    const int r0 = t >> 6;
    for (int rr = 0; rr < 64; rr += 4) {
        const int r = rr + r0;
        float v = W[(size_t)(k0 + r) * N + n0 + c];
#pragma unroll
        for (int q = 0; q < 16; ++q) v += As[r][q] * Bs[q][c];
        tile[r][c] = v;
    }
    __syncthreads();
    for (int rr = 0; rr < 64; rr += 4) {
        const int r = rr + r0;
        WT[(size_t)(n0 + r) * K + k0 + c] = f2bf(tile[c][r]);
    }
}

// ---------------- fused gate+up GEMM + relu-gate epilogue ----------------
// Xb: [M,2048] bf16, WgT/WuT: [8192,2048] bf16 (row n, contiguous k)
// X3[m,f] = relu(Xb@WgT^T + bg) * (Xb@WuT^T + bu), bf16
__global__ __launch_bounds__(256, 2)
void gemm_gateup(const unsigned short* __restrict__ Xb,
                 const unsigned short* __restrict__ WgT,
                 const unsigned short* __restrict__ WuT,
                 const float* __restrict__ bg, const float* __restrict__ bu,
                 unsigned short* __restrict__ X3) {
    constexpr int K = 2048, F = 8192;
    __shared__ __align__(16) unsigned short As[128 * 32];
    __shared__ __align__(16) unsigned short Bg[128 * 32];
    __shared__ __align__(16) unsigned short Bu[128 * 32];

    const int tid = threadIdx.x;
    const int lane = tid & 63;
    const int wave = tid >> 6;
    const int wm = (wave >> 1) * 64;
    const int wn = (wave & 1) * 64;
    const int l16 = lane & 15;
    const int quad = lane >> 4;

    const int m0 = blockIdx.x * 128;
    const int n0 = blockIdx.y * 128;

    const unsigned short* Ag = Xb + (size_t)m0 * K;
    const unsigned short* Gg = WgT + (size_t)n0 * K;
    const unsigned short* Ug = WuT + (size_t)n0 * K;

    // staging: 512 chunks of 16B per tile; thread stages chunks tid and tid+256.
    // LDS position = chunk index (contiguous, required by global_load_lds);
    // global source chunk column = (pos ^ sw_row(r)) -> swizzled storage.
    const int c1 = tid, c2 = tid + 256;
    const int r1 = c1 >> 2, o1 = (((c1 & 3) ^ sw_row(r1)) & 3) * 8;
    const int r2 = c2 >> 2, o2 = (((c2 & 3) ^ sw_row(r2)) & 3) * 8;

    f32x4 accg[4][4] = {};
    f32x4 accu[4][4] = {};

    for (int k0 = 0; k0 < K; k0 += 32) {
        gload16(Ag + (size_t)r1 * K + k0 + o1, As + c1 * 8);
        gload16(Ag + (size_t)r2 * K + k0 + o2, As + c2 * 8);
        gload16(Gg + (size_t)r1 * K + k0 + o1, Bg + c1 * 8);
        gload16(Gg + (size_t)r2 * K + k0 + o2, Bg + c2 * 8);
        gload16(Ug + (size_t)r1 * K + k0 + o1, Bu + c1 * 8);
        gload16(Ug + (size_t)r2 * K + k0 + o2, Bu + c2 * 8);
        __syncthreads();  // drains vmcnt(0): LDS tiles ready
        bf16x8 af[4], gf[4], uf[4];
#pragma unroll
        for (int i = 0; i < 4; ++i) {
            const int ra = wm + i * 16 + l16;
            const int rb = wn + i * 16 + l16;
            const int pa = (quad ^ sw_row(ra)) * 8;
            const int pb = (quad ^ sw_row(rb)) * 8;
            af[i] = *(const bf16x8*)(As + ra * 32 + pa);
            gf[i] = *(const bf16x8*)(Bg + rb * 32 + pb);
            uf[i] = *(const bf16x8*)(Bu + rb * 32 + pb);
        }
#pragma unroll
        for (int i = 0; i < 4; ++i)
#pragma unroll
            for (int j = 0; j < 4; ++j) {
                accg[i][j] = MFMA16(af[i], gf[j], accg[i][j]);
                accu[i][j] = MFMA16(af[i], uf[j], accu[i][j]);
            }
        __syncthreads();  // all reads done before next stage overwrites
    }

    // epilogue: C/D layout col = lane&15, row = quad*4 + reg  [m89/m91-verified]
#pragma unroll
    for (int j = 0; j < 4; ++j) {
        const int col = n0 + wn + j * 16 + l16;
        const float bgv = bg[col];
        const float buv = bu[col];
#pragma unroll
        for (int i = 0; i < 4; ++i) {
            const int rowb = m0 + wm + i * 16 + quad * 4;
#pragma unroll
            for (int r = 0; r < 4; ++r) {
                float g = accg[i][j][r] + bgv;
                float u = accu[i][j][r] + buv;
                g = g > 0.f ? g : 0.f;
                X3[(size_t)(rowb + r) * F + col] = f2bf(g * u);
            }
        }
    }
}

// ---------------- down GEMM: out = X3@WdT^T + bd, fp32 out ----------------
// X3: [M,8192] bf16, WdT: [2048,8192] bf16
__global__ __launch_bounds__(256, 2)
void gemm_down(const unsigned short* __restrict__ X3,
               const unsigned short* __restrict__ WdT,
               const float* __restrict__ bd, float* __restrict__ out) {
    constexpr int K = 8192, N = 2048;
    __shared__ __align__(16) unsigned short As[128 * 32];
    __shared__ __align__(16) unsigned short Bs[128 * 32];

    const int tid = threadIdx.x;
    const int lane = tid & 63;
    const int wave = tid >> 6;
    const int wm = (wave >> 1) * 64;
    const int wn = (wave & 1) * 64;
    const int l16 = lane & 15;
    const int quad = lane >> 4;

    const int m0 = blockIdx.x * 128;
    const int n0 = blockIdx.y * 128;

    const unsigned short* Ag = X3 + (size_t)m0 * K;
    const unsigned short* Bgp = WdT + (size_t)n0 * K;

    const int c1 = tid, c2 = tid + 256;
    const int r1 = c1 >> 2, o1 = (((c1 & 3) ^ sw_row(r1)) & 3) * 8;
    const int r2 = c2 >> 2, o2 = (((c2 & 3) ^ sw_row(r2)) & 3) * 8;

    f32x4 acc[4][4] = {};

    for (int k0 = 0; k0 < K; k0 += 32) {
        gload16(Ag + (size_t)r1 * K + k0 + o1, As + c1 * 8);
        gload16(Ag + (size_t)r2 * K + k0 + o2, As + c2 * 8);
        gload16(Bgp + (size_t)r1 * K + k0 + o1, Bs + c1 * 8);
        gload16(Bgp + (size_t)r2 * K + k0 + o2, Bs + c2 * 8);
        __syncthreads();
        bf16x8 af[4], bfr[4];
#pragma unroll
        for (int i = 0; i < 4; ++i) {
            const int ra = wm + i * 16 + l16;
            const int rb = wn + i * 16 + l16;
            const int pa = (quad ^ sw_row(ra)) * 8;
            const int pb = (quad ^ sw_row(rb)) * 8;
            af[i] = *(const bf16x8*)(As + ra * 32 + pa);
            bfr[i] = *(const bf16x8*)(Bs + rb * 32 + pb);
        }
#pragma unroll
        for (int i = 0; i < 4; ++i)
#pragma unroll
            for (int j = 0; j < 4; ++j)
                acc[i][j] = MFMA16(af[i], bfr[j], acc[i][j]);
        __syncthreads();
    }

#pragma unroll
    for (int j = 0; j < 4; ++j) {
        const int col = n0 + wn + j * 16 + l16;
        const float bdv = bd[col];
#pragma unroll
        for (int i = 0; i < 4; ++i) {
            const int rowb = m0 + wm + i * 16 + quad * 4;
#pragma unroll
            for (int r = 0; r < 4; ++r)
                out[(size_t)(rowb + r) * N + col] = acc[i][j][r] + bdv;
        }
    }
}

extern "C" void kernel_launch(void* const* d_in, const int* in_sizes, int n_in,
                              void* d_out, int out_size, void* d_ws, size_t ws_size,
                              hipStream_t stream) {
    const float* x1      = (const float*)d_in[0];
    const float* w_gate  = (const float*)d_in[1];
    const float* b_gate  = (const float*)d_in[2];
    const float* a_gate  = (const float*)d_in[3];
    const float* lb_gate = (const float*)d_in[4];
    const float* w_up    = (const float*)d_in[5];
    const float* b_up    = (const float*)d_in[6];
    const float* a_up    = (const float*)d_in[7];
    const float* lb_up   = (const float*)d_in[8];
    const float* w_down  = (const float*)d_in[9];
    const float* b_down  = (const float*)d_in[10];
    const float* a_down  = (const float*)d_in[11];
    const float* lb_down = (const float*)d_in[12];

    constexpr int M = 8192, D = 2048, F = 8192;

    // workspace layout (256 MiB total)
    char* ws = (char*)d_ws;
    unsigned short* Xb  = (unsigned short*)ws;                     // [M,D]  bf16  32 MiB
    unsigned short* WgT = (unsigned short*)(ws + 33554432ULL);     // [F,D]  bf16  32 MiB
    unsigned short* WuT = (unsigned short*)(ws + 67108864ULL);     // [F,D]  bf16  32 MiB
    unsigned short* WdT = (unsigned short*)(ws + 100663296ULL);    // [D,F]  bf16  32 MiB
    unsigned short* X3  = (unsigned short*)(ws + 134217728ULL);    // [M,F]  bf16 128 MiB

    cast_x_kernel<<<dim3((M * D) / 4 / 256), dim3(256), 0, stream>>>(
        (const float4*)x1, (ushort4*)Xb);
    prep_wT<<<dim3(D / 64, F / 64), dim3(256), 0, stream>>>(w_gate, a_gate, lb_gate, WgT, D, F);
    prep_wT<<<dim3(D / 64, F / 64), dim3(256), 0, stream>>>(w_up, a_up, lb_up, WuT, D, F);
    prep_wT<<<dim3(F / 64, D / 64), dim3(256), 0, stream>>>(w_down, a_down, lb_down, WdT, F, D);

    gemm_gateup<<<dim3(M / 128, F / 128), dim3(256), 0, stream>>>(
        Xb, WgT, WuT, b_gate, b_up, X3);
    gemm_down<<<dim3(M / 128, D / 128), dim3(256), 0, stream>>>(
        X3, WdT, b_down, (float*)d_out);
}

// Round 3
// 1069.574 us; speedup vs baseline: 1.1519x; 1.1283x over previous
//
#include <hip/hip_runtime.h>

// bf16 storage type = ushort (raw bits); avoids hip_bf16.h dependency.
typedef __bf16 bf16x8 __attribute__((ext_vector_type(8)));
typedef float f32x4 __attribute__((ext_vector_type(4)));

#define MFMA16(a, b, c) __builtin_amdgcn_mfma_f32_16x16x32_bf16((a), (b), (c), 0, 0, 0)

__device__ __forceinline__ unsigned short f2bf(float f) {
    // round-to-nearest-even bf16 (finite inputs)
    unsigned int u = __float_as_uint(f);
    u += 0x7fffu + ((u >> 16) & 1u);
    return (unsigned short)(u >> 16);
}

__device__ __forceinline__ void gload16(const unsigned short* g, unsigned short* l) {
    // async global->LDS, 16B per lane; LDS dest = wave-uniform base + lane*16
    __builtin_amdgcn_global_load_lds(
        (__attribute__((address_space(1))) void*)(void*)g,
        (__attribute__((address_space(3))) void*)(void*)l,
        16, 0, 0);
}

// BK=64 tile: 128 rows x 64 bf16 = 128 B/row = 8 chunks of 16 B.
// Swizzle: global chunk (r,c) stored at LDS position (r, c ^ (r&7)).
// Reader at fixed (k-half, quad) then spreads uniformly over all 8
// bank-quads across 16 consecutive rows -> conflict-free (R2: verified 0).

// ---------------- prep: x fp32 -> bf16 ----------------
__global__ void cast_x_kernel(const float4* __restrict__ x, ushort4* __restrict__ xb) {
    const size_t i = (size_t)blockIdx.x * 256 + threadIdx.x;
    const float4 v = x[i];
    ushort4 o;
    o.x = f2bf(v.x); o.y = f2bf(v.y); o.z = f2bf(v.z); o.w = f2bf(v.w);
    xb[i] = o;
}

// ---------------- prep: WT[n,k] = W[k,n] + sum_r A[k,r]*B2[r,n], bf16 out ----
// W: [K,N] fp32, A: [K,16] fp32, B2: [16,N] fp32, WT: [N,K] bf16
__global__ void prep_wT(const float* __restrict__ W, const float* __restrict__ A,
                        const float* __restrict__ B2, unsigned short* __restrict__ WT,
                        const int K, const int N) {
    __shared__ float tile[64][65];
    __shared__ float As[64][16];
    __shared__ float Bs[16][64];
    const int t = threadIdx.x;         // 256 threads
    const int k0 = blockIdx.x * 64;
    const int n0 = blockIdx.y * 64;

    for (int i = t; i < 64 * 16; i += 256)
        As[i >> 4][i & 15] = A[(size_t)(k0 + (i >> 4)) * 16 + (i & 15)];
    for (int i = t; i < 16 * 64; i += 256)
        Bs[i >> 6][i & 63] = B2[(size_t)(i >> 6) * N + n0 + (i & 63)];
    __syncthreads();

    const int c = t & 63;
    const int r0 = t >> 6;
    for (int rr = 0; rr < 64; rr += 4) {
        const int r = rr + r0;
        float v = W[(size_t)(k0 + r) * N + n0 + c];
#pragma unroll
        for (int q = 0; q < 16; ++q) v += As[r][q] * Bs[q][c];
        tile[r][c] = v;
    }
    __syncthreads();
    for (int rr = 0; rr < 64; rr += 4) {
        const int r = rr + r0;
        WT[(size_t)(n0 + r) * K + k0 + c] = f2bf(tile[c][r]);
    }
}

// ---------------- fused gate+up GEMM + relu-gate epilogue ----------------
// Xb: [M,2048] bf16, WgT/WuT: [8192,2048] bf16 (row n, contiguous k)
// X3[m,f] = relu(Xb@WgT^T + bg) * (Xb@WuT^T + bu), bf16
__global__ __launch_bounds__(256, 2)
void gemm_gateup(const unsigned short* __restrict__ Xb,
                 const unsigned short* __restrict__ WgT,
                 const unsigned short* __restrict__ WuT,
                 const float* __restrict__ bg, const float* __restrict__ bu,
                 unsigned short* __restrict__ X3) {
    constexpr int K = 2048, F = 8192;
    constexpr int BK = 64;
    __shared__ __align__(16) unsigned short As[128 * BK];
    __shared__ __align__(16) unsigned short Bg[128 * BK];
    __shared__ __align__(16) unsigned short Bu[128 * BK];

    const int tid = threadIdx.x;
    const int lane = tid & 63;
    const int wave = tid >> 6;
    const int wm = (wave >> 1) * 64;
    const int wn = (wave & 1) * 64;
    const int l16 = lane & 15;
    const int quad = lane >> 4;

    const int m0 = blockIdx.x * 128;
    const int n0 = blockIdx.y * 128;

    const unsigned short* Ag = Xb + (size_t)m0 * K;
    const unsigned short* Gg = WgT + (size_t)n0 * K;
    const unsigned short* Ug = WuT + (size_t)n0 * K;

    // staging: 1024 chunks of 16 B per 16-KB tile; thread stages chunks
    // tid + j*256 (j=0..3). LDS position contiguous (global_load_lds rule);
    // global source column = (pos ^ (row&7)).
    int srow[4], soff[4];
#pragma unroll
    for (int j = 0; j < 4; ++j) {
        const int c = tid + j * 256;
        srow[j] = c >> 3;
        soff[j] = ((c & 7) ^ (srow[j] & 7)) * 8;
    }

    f32x4 accg[4][4] = {};
    f32x4 accu[4][4] = {};

    for (int k0 = 0; k0 < K; k0 += BK) {
#pragma unroll
        for (int j = 0; j < 4; ++j)
            gload16(Ag + (size_t)srow[j] * K + k0 + soff[j], As + (tid + j * 256) * 8);
#pragma unroll
        for (int j = 0; j < 4; ++j)
            gload16(Gg + (size_t)srow[j] * K + k0 + soff[j], Bg + (tid + j * 256) * 8);
#pragma unroll
        for (int j = 0; j < 4; ++j)
            gload16(Ug + (size_t)srow[j] * K + k0 + soff[j], Bu + (tid + j * 256) * 8);
        __syncthreads();  // drains vmcnt(0): LDS tiles ready
#pragma unroll
        for (int h = 0; h < 2; ++h) {  // two 32-k halves per staged tile
            bf16x8 af[4], gf[4], uf[4];
#pragma unroll
            for (int i = 0; i < 4; ++i) {
                const int ra = wm + i * 16 + l16;
                const int rb = wn + i * 16 + l16;
                const int pa = ((h * 4 + quad) ^ (ra & 7)) * 8;
                const int pb = ((h * 4 + quad) ^ (rb & 7)) * 8;
                af[i] = *(const bf16x8*)(As + ra * BK + pa);
                gf[i] = *(const bf16x8*)(Bg + rb * BK + pb);
                uf[i] = *(const bf16x8*)(Bu + rb * BK + pb);
            }
#pragma unroll
            for (int i = 0; i < 4; ++i)
#pragma unroll
                for (int j = 0; j < 4; ++j) {
                    accg[i][j] = MFMA16(af[i], gf[j], accg[i][j]);
                    accu[i][j] = MFMA16(af[i], uf[j], accu[i][j]);
                }
        }
        __syncthreads();  // all reads done before next stage overwrites
    }

    // epilogue: C/D layout col = lane&15, row = quad*4 + reg  [m89/m91-verified]
#pragma unroll
    for (int j = 0; j < 4; ++j) {
        const int col = n0 + wn + j * 16 + l16;
        const float bgv = bg[col];
        const float buv = bu[col];
#pragma unroll
        for (int i = 0; i < 4; ++i) {
            const int rowb = m0 + wm + i * 16 + quad * 4;
#pragma unroll
            for (int r = 0; r < 4; ++r) {
                float g = accg[i][j][r] + bgv;
                float u = accu[i][j][r] + buv;
                g = g > 0.f ? g : 0.f;
                X3[(size_t)(rowb + r) * F + col] = f2bf(g * u);
            }
        }
    }
}

// ---------------- down GEMM: out = X3@WdT^T + bd, fp32 out ----------------
// X3: [M,8192] bf16, WdT: [2048,8192] bf16
__global__ __launch_bounds__(256, 3)
void gemm_down(const unsigned short* __restrict__ X3,
               const unsigned short* __restrict__ WdT,
               const float* __restrict__ bd, float* __restrict__ out) {
    constexpr int K = 8192, N = 2048;
    constexpr int BK = 64;
    __shared__ __align__(16) unsigned short As[128 * BK];
    __shared__ __align__(16) unsigned short Bs[128 * BK];

    const int tid = threadIdx.x;
    const int lane = tid & 63;
    const int wave = tid >> 6;
    const int wm = (wave >> 1) * 64;
    const int wn = (wave & 1) * 64;
    const int l16 = lane & 15;
    const int quad = lane >> 4;

    const int m0 = blockIdx.x * 128;
    const int n0 = blockIdx.y * 128;

    const unsigned short* Ag = X3 + (size_t)m0 * K;
    const unsigned short* Bgp = WdT + (size_t)n0 * K;

    int srow[4], soff[4];
#pragma unroll
    for (int j = 0; j < 4; ++j) {
        const int c = tid + j * 256;
        srow[j] = c >> 3;
        soff[j] = ((c & 7) ^ (srow[j] & 7)) * 8;
    }

    f32x4 acc[4][4] = {};

    for (int k0 = 0; k0 < K; k0 += BK) {
#pragma unroll
        for (int j = 0; j < 4; ++j)
            gload16(Ag + (size_t)srow[j] * K + k0 + soff[j], As + (tid + j * 256) * 8);
#pragma unroll
        for (int j = 0; j < 4; ++j)
            gload16(Bgp + (size_t)srow[j] * K + k0 + soff[j], Bs + (tid + j * 256) * 8);
        __syncthreads();
#pragma unroll
        for (int h = 0; h < 2; ++h) {
            bf16x8 af[4], bfr[4];
#pragma unroll
            for (int i = 0; i < 4; ++i) {
                const int ra = wm + i * 16 + l16;
                const int rb = wn + i * 16 + l16;
                const int pa = ((h * 4 + quad) ^ (ra & 7)) * 8;
                const int pb = ((h * 4 + quad) ^ (rb & 7)) * 8;
                af[i] = *(const bf16x8*)(As + ra * BK + pa);
                bfr[i] = *(const bf16x8*)(Bs + rb * BK + pb);
            }
#pragma unroll
            for (int i = 0; i < 4; ++i)
#pragma unroll
                for (int j = 0; j < 4; ++j)
                    acc[i][j] = MFMA16(af[i], bfr[j], acc[i][j]);
        }
        __syncthreads();
    }

#pragma unroll
    for (int j = 0; j < 4; ++j) {
        const int col = n0 + wn + j * 16 + l16;
        const float bdv = bd[col];
#pragma unroll
        for (int i = 0; i < 4; ++i) {
            const int rowb = m0 + wm + i * 16 + quad * 4;
#pragma unroll
            for (int r = 0; r < 4; ++r)
                out[(size_t)(rowb + r) * N + col] = acc[i][j][r] + bdv;
        }
    }
}

extern "C" void kernel_launch(void* const* d_in, const int* in_sizes, int n_in,
                              void* d_out, int out_size, void* d_ws, size_t ws_size,
                              hipStream_t stream) {
    const float* x1      = (const float*)d_in[0];
    const float* w_gate  = (const float*)d_in[1];
    const float* b_gate  = (const float*)d_in[2];
    const float* a_gate  = (const float*)d_in[3];
    const float* lb_gate = (const float*)d_in[4];
    const float* w_up    = (const float*)d_in[5];
    const float* b_up    = (const float*)d_in[6];
    const float* a_up    = (const float*)d_in[7];
    const float* lb_up   = (const float*)d_in[8];
    const float* w_down  = (const float*)d_in[9];
    const float* b_down  = (const float*)d_in[10];
    const float* a_down  = (const float*)d_in[11];
    const float* lb_down = (const float*)d_in[12];

    constexpr int M = 8192, D = 2048, F = 8192;

    // workspace layout (256 MiB total)
    char* ws = (char*)d_ws;
    unsigned short* Xb  = (unsigned short*)ws;                     // [M,D]  bf16  32 MiB
    unsigned short* WgT = (unsigned short*)(ws + 33554432ULL);     // [F,D]  bf16  32 MiB
    unsigned short* WuT = (unsigned short*)(ws + 67108864ULL);     // [F,D]  bf16  32 MiB
    unsigned short* WdT = (unsigned short*)(ws + 100663296ULL);    // [D,F]  bf16  32 MiB
    unsigned short* X3  = (unsigned short*)(ws + 134217728ULL);    // [M,F]  bf16 128 MiB

    cast_x_kernel<<<dim3((M * D) / 4 / 256), dim3(256), 0, stream>>>(
        (const float4*)x1, (ushort4*)Xb);
    prep_wT<<<dim3(D / 64, F / 64), dim3(256), 0, stream>>>(w_gate, a_gate, lb_gate, WgT, D, F);
    prep_wT<<<dim3(D / 64, F / 64), dim3(256), 0, stream>>>(w_up, a_up, lb_up, WuT, D, F);
    prep_wT<<<dim3(F / 64, D / 64), dim3(256), 0, stream>>>(w_down, a_down, lb_down, WdT, F, D);

    gemm_gateup<<<dim3(M / 128, F / 128), dim3(256), 0, stream>>>(
        Xb, WgT, WuT, b_gate, b_up, X3);
    gemm_down<<<dim3(M / 128, D / 128), dim3(256), 0, stream>>>(
        X3, WdT, b_down, (float*)d_out);
}